// Round 1
// baseline (182.747 us; speedup 1.0000x reference)
//
#include <hip/hip_runtime.h>

#define B_  4
#define S_  1024
#define D_  1024
#define H_  16
#define HD_ 64
#define EPS_ 1e-5f

typedef _Float16 f16x8 __attribute__((ext_vector_type(8)));
typedef _Float16 f16x4 __attribute__((ext_vector_type(4)));
typedef __bf16 bf16x8 __attribute__((ext_vector_type(8)));
typedef float  f32x4  __attribute__((ext_vector_type(4)));
typedef unsigned short ushort8v __attribute__((ext_vector_type(8)));

static __device__ __forceinline__ unsigned short f2bf(float f) {
  union { float f; unsigned u; } v; v.f = f;
  unsigned r = v.u + 0x7fffu + ((v.u >> 16) & 1u);
  return (unsigned short)(r >> 16);
}
static __device__ __forceinline__ float bf2f(unsigned short u) {
  union { unsigned u; float f; } v; v.u = ((unsigned)u) << 16;
  return v.f;
}

// async global->LDS, 16B per lane; LDS dest is wave-uniform base + lane*16
#define GLD16(gp, lp) __builtin_amdgcn_global_load_lds( \
    (const __attribute__((address_space(1))) void*)(gp), \
    (__attribute__((address_space(3))) void*)(lp), 16, 0, 0)

// ---------------------------------------------------------------- convert ---
__global__ __launch_bounds__(256) void cvt_all(
    const float* __restrict__ x,  _Float16* __restrict__ xh,
    const float* __restrict__ Wq, _Float16* __restrict__ wqh,
    const float* __restrict__ Wk, _Float16* __restrict__ wkh,
    const float* __restrict__ Wv, _Float16* __restrict__ wvh,
    float* __restrict__ Vtail) {
  int bid = blockIdx.x;
  if (bid >= 7168) {                    // 4 blocks zero Vtail (B*H*HD f32)
    int i = (bid - 7168) * 1024 + threadIdx.x * 4;
    *(float4*)(Vtail + i) = make_float4(0.f, 0.f, 0.f, 0.f);
    return;
  }
  const float* src; _Float16* dst; int base;
  if (bid < 4096)      { src = x;  dst = xh;  base = bid; }
  else if (bid < 5120) { src = Wq; dst = wqh; base = bid - 4096; }
  else if (bid < 6144) { src = Wk; dst = wkh; base = bid - 5120; }
  else                 { src = Wv; dst = wvh; base = bid - 6144; }
  int i = base * 1024 + threadIdx.x * 4;
  float4 f = *(const float4*)(src + i);
  f16x4 h;
  h.x = (_Float16)f.x; h.y = (_Float16)f.y; h.z = (_Float16)f.z; h.w = (_Float16)f.w;
  *(f16x4*)(dst + i) = h;
}

// ---------------------------------------------- GEMM 128x64, BK=64 (gemm1) ---
// R9-VERIFIED verbatim.
__global__ __launch_bounds__(256, 2) void gemm_bt_bias(
    const _Float16* __restrict__ A,
    const _Float16* __restrict__ B0, const float* __restrict__ bias0,
    _Float16* __restrict__ C0,
    const _Float16* __restrict__ B1, const float* __restrict__ bias1,
    _Float16* __restrict__ C1,
    int M, int N, int K)
{
  const _Float16* Bm = blockIdx.z ? B1 : B0;
  const float* bias  = blockIdx.z ? bias1 : bias0;
  _Float16* C        = blockIdx.z ? C1 : C0;

  __shared__ _Float16 As[2 * 128 * 32];   // 16 KB
  __shared__ _Float16 Bs[2 * 64 * 32];    //  8 KB

  int tid  = threadIdx.x;
  int lane = tid & 63;
  int wave = tid >> 6;
  int wm = wave >> 1, wn = wave & 1;
  int qd = lane >> 4, l15 = lane & 15;

  long row0 = (long)blockIdx.y * 128;
  long col0 = (long)blockIdx.x * 64;

  int r_a = tid >> 2;
  int c_a = (tid & 3) * 8;

  f32x4 acc[4][2] = {};

  for (int kk = 0; kk < K; kk += 64) {
    GLD16(A  + (row0 + r_a) * K + kk + c_a,           As + tid * 8);
    GLD16(A  + (row0 + 64 + r_a) * K + kk + c_a,      As + 2048 + tid * 8);
    GLD16(A  + (row0 + r_a) * K + kk + 32 + c_a,      As + 4096 + tid * 8);
    GLD16(A  + (row0 + 64 + r_a) * K + kk + 32 + c_a, As + 6144 + tid * 8);
    GLD16(Bm + (col0 + r_a) * K + kk + c_a,           Bs + tid * 8);
    GLD16(Bm + (col0 + r_a) * K + kk + 32 + c_a,      Bs + 2048 + tid * 8);
    __syncthreads();

    for (int ks = 0; ks < 2; ks++) {
      f16x8 af[4], bfr[2];
      for (int t = 0; t < 4; t++)
        af[t]  = *(const f16x8*)(As + ks * 4096 + (wm * 64 + t * 16 + l15) * 32 + qd * 8);
      for (int j = 0; j < 2; j++)
        bfr[j] = *(const f16x8*)(Bs + ks * 2048 + (wn * 32 + j * 16 + l15) * 32 + qd * 8);
      for (int i = 0; i < 4; i++)
        for (int j = 0; j < 2; j++)
          acc[i][j] = __builtin_amdgcn_mfma_f32_16x16x32_f16(af[i], bfr[j], acc[i][j], 0, 0, 0);
    }
    __syncthreads();
  }

  for (int i = 0; i < 4; i++) {
    long row = row0 + wm * 64 + i * 16 + qd * 4;
    for (int j = 0; j < 2; j++) {
      long col = col0 + wn * 32 + j * 16 + l15;
      float bv = bias[col];
      for (int r = 0; r < 4; r++)
        C[(row + r) * N + col] = (_Float16)(acc[i][j][r] + bv);
    }
  }
}

// --------------------------------------------- GEMM 128x128, BK=64 (gemm2) ---
// R9-VERIFIED verbatim.
__global__ __launch_bounds__(256, 2) void gemm_bt_bias128(
    const _Float16* __restrict__ A,
    const _Float16* __restrict__ B0, const float* __restrict__ bias0,
    _Float16* __restrict__ C0,
    const _Float16* __restrict__ B1, const float* __restrict__ bias1,
    _Float16* __restrict__ C1,
    int M, int N, int K)
{
  const _Float16* Bm = blockIdx.z ? B1 : B0;
  const float* bias  = blockIdx.z ? bias1 : bias0;
  _Float16* C        = blockIdx.z ? C1 : C0;

  __shared__ _Float16 As[2 * 128 * 32];   // 16 KB
  __shared__ _Float16 Bs[2 * 128 * 32];   // 16 KB

  int tid  = threadIdx.x;
  int lane = tid & 63;
  int wave = tid >> 6;
  int wm = wave >> 1, wn = wave & 1;
  int qd = lane >> 4, l15 = lane & 15;

  long row0 = (long)blockIdx.y * 128;
  long col0 = (long)blockIdx.x * 128;

  int r_a = tid >> 2;
  int c_a = (tid & 3) * 8;

  f32x4 acc[4][4] = {};

  for (int kk = 0; kk < K; kk += 64) {
    GLD16(A  + (row0 + r_a) * K + kk + c_a,           As + tid * 8);
    GLD16(A  + (row0 + 64 + r_a) * K + kk + c_a,      As + 2048 + tid * 8);
    GLD16(A  + (row0 + r_a) * K + kk + 32 + c_a,      As + 4096 + tid * 8);
    GLD16(A  + (row0 + 64 + r_a) * K + kk + 32 + c_a, As + 6144 + tid * 8);
    GLD16(Bm + (col0 + r_a) * K + kk + c_a,           Bs + tid * 8);
    GLD16(Bm + (col0 + 64 + r_a) * K + kk + c_a,      Bs + 2048 + tid * 8);
    GLD16(Bm + (col0 + r_a) * K + kk + 32 + c_a,      Bs + 4096 + tid * 8);
    GLD16(Bm + (col0 + 64 + r_a) * K + kk + 32 + c_a, Bs + 6144 + tid * 8);
    __syncthreads();

    for (int ks = 0; ks < 2; ks++) {
      f16x8 af[4], bfr[4];
      for (int t = 0; t < 4; t++) {
        af[t]  = *(const f16x8*)(As + ks * 4096 + (wm * 64 + t * 16 + l15) * 32 + qd * 8);
        bfr[t] = *(const f16x8*)(Bs + ks * 4096 + (wn * 64 + t * 16 + l15) * 32 + qd * 8);
      }
      for (int i = 0; i < 4; i++)
        for (int j = 0; j < 4; j++)
          acc[i][j] = __builtin_amdgcn_mfma_f32_16x16x32_f16(af[i], bfr[j], acc[i][j], 0, 0, 0);
    }
    __syncthreads();
  }

  for (int i = 0; i < 4; i++) {
    long row = row0 + wm * 64 + i * 16 + qd * 4;
    for (int j = 0; j < 4; j++) {
      long col = col0 + wn * 64 + j * 16 + l15;
      float bv = bias[col];
      for (int r = 0; r < 4; r++)
        C[(row + r) * N + col] = (_Float16)(acc[i][j][r] + bv);
    }
  }
}

// ----------------------------------------------------------------- LN qkv ---
// R5/R9-VERIFIED verbatim.
__global__ __launch_bounds__(256) void ln_qkv(
    const _Float16* __restrict__ qh,
    const _Float16* __restrict__ kh,
    const _Float16* __restrict__ vh,
    const float* __restrict__ ln_g, const float* __restrict__ ln_b,
    const int* __restrict__ seq_len,
    _Float16* __restrict__ Qn,
    _Float16* __restrict__ Kn,
    unsigned short* __restrict__ Vt,
    float* __restrict__ Vtail)
{
  __shared__ unsigned short Vls[256][68];   // bf16, padded ~34 KB
  int tid = threadIdx.x;
  int s0 = blockIdx.x * 256;
  int h = blockIdx.y, b = blockIdx.z;
  long bh = (long)b * H_ + h;
  long s = s0 + tid;
  long inbase  = ((long)b * S_ + s) * D_ + (long)h * HD_;
  long outbase = (bh * S_ + s) * HD_;

  // ---- prefetch ALL of q,k,v for this row (24 x 16B loads in flight) ----
  f16x8 rq[8], rk[8], rv[8];
  for (int i = 0; i < 8; i++) {
    rq[i] = *(const f16x8*)(qh + inbase + i * 8);
    rk[i] = *(const f16x8*)(kh + inbase + i * 8);
    rv[i] = *(const f16x8*)(vh + inbase + i * 8);
  }

  // ---- q ----
  {
    float sum = 0.f, sq = 0.f;
    for (int i = 0; i < 8; i++)
      for (int j = 0; j < 8; j++) { float xv = (float)rq[i][j]; sum += xv; sq = fmaf(xv, xv, sq); }
    float m = sum * (1.f / 64.f);
    float inv = rsqrtf(sq * (1.f / 64.f) - m * m + EPS_);
    for (int i = 0; i < 8; i++) {
      f16x8 o;
      for (int j = 0; j < 8; j++)
        o[j] = (_Float16)(((float)rq[i][j] - m) * inv * ln_g[i * 8 + j] + ln_b[i * 8 + j]);
      *(f16x8*)(Qn + outbase + i * 8) = o;
    }
  }
  // ---- k ----
  {
    float sum = 0.f, sq = 0.f;
    for (int i = 0; i < 8; i++)
      for (int j = 0; j < 8; j++) { float xv = (float)rk[i][j]; sum += xv; sq = fmaf(xv, xv, sq); }
    float m = sum * (1.f / 64.f);
    float inv = rsqrtf(sq * (1.f / 64.f) - m * m + EPS_);
    for (int i = 0; i < 8; i++) {
      f16x8 o;
      for (int j = 0; j < 8; j++)
        o[j] = (_Float16)(((float)rk[i][j] - m) * inv * ln_g[i * 8 + j] + ln_b[i * 8 + j]);
      *(f16x8*)(Kn + outbase + i * 8) = o;
    }
  }
  // ---- v (normalize to bf16 into LDS, then transposed write-out) ----
  {
    float sum = 0.f, sq = 0.f;
    for (int i = 0; i < 8; i++)
      for (int j = 0; j < 8; j++) { float xv = (float)rv[i][j]; sum += xv; sq = fmaf(xv, xv, sq); }
    float m = sum * (1.f / 64.f);
    float inv = rsqrtf(sq * (1.f / 64.f) - m * m + EPS_);
    for (int i = 0; i < 8; i++)
      for (int j = 0; j < 8; j++)
        Vls[tid][i * 8 + j] = f2bf(((float)rv[i][j] - m) * inv * ln_g[i * 8 + j] + ln_b[i * 8 + j]);
  }
  __syncthreads();
  int d = tid >> 2, sc = tid & 3;
  int len = seq_len[b];
  long vbase = (bh * HD_ + d) * S_ + s0 + sc * 64;
  float tsum = 0.f;
  for (int j0 = 0; j0 < 64; j0 += 8) {
    ushort8v w;
    for (int jj = 0; jj < 8; jj++) {
      unsigned short ub = Vls[sc * 64 + j0 + jj][d];
      w[jj] = ub;
      if (s0 + sc * 64 + j0 + jj >= len) tsum += bf2f(ub);
    }
    *(ushort8v*)(Vt + vbase + j0) = w;
  }
  if (s0 + sc * 64 + 64 > len)            // any tail rows in this chunk
    atomicAdd(&Vtail[bh * HD_ + d], tsum);
}

// -------------------------------------------------------------- attention ---
// R10: double-buffered K/V with prefetch-before-compute (T3 minimum 2-phase).
// Old structure was stage(t) -> sync -> compute(t) -> sync: every tile began
// with a serial vmcnt(0) drain (~200-900 cyc) with nothing overlapped, at
// only 8 waves/CU (grid-capped 2 blocks/CU) -> MfmaUtil 11 / VALUBusy 30 /
// HBM 8% = latency-bound. Now: stage(t+1 into alt buf) is issued FIRST, the
// whole tile's compute runs, and the single end-of-tile barrier drains loads
// that have been in flight all along. Also: mask check (kg<len) hoisted to a
// block-uniform branch -- only the last (partial) tile pays cmp/cndmask.
__global__ __launch_bounds__(256, 2) void attn(
    const _Float16* __restrict__ Qn,
    const _Float16* __restrict__ Kn,
    const unsigned short* __restrict__ Vt,
    const float* __restrict__ Vtail,
    const int* __restrict__ seq_len,
    float* __restrict__ out)
{
  __shared__ _Float16 Ks[2][2][64 * 32];        // [buf][d-half][key*32]  16 KB
  __shared__ unsigned short Vts[2][2][64 * 32]; // [buf][key-half][d*32]  16 KB
  __shared__ unsigned short Ps[4][32 * 72];     // per-wave P [32m][72]   18 KB

  int tid = threadIdx.x, lane = tid & 63, wave = tid >> 6;
  int qd = lane >> 4, l15 = lane & 15;
  int b = blockIdx.x;                        // b fastest: len load-balance
  int h = blockIdx.y;
  int q0 = blockIdx.z * 128;
  long bh = (long)b * H_ + h;
  int len = seq_len[b];
  int ntile = (len + 63) >> 6;               // tiles containing any key < len

  int skey = tid >> 2;
  int schunk = (tid & 3) * 8;

  f16x8 qf[2][2];
  for (int mt = 0; mt < 2; mt++) {
    const _Float16* qp = Qn + (bh * S_ + q0 + wave * 32 + mt * 16 + l15) * HD_;
    qf[mt][0] = *(const f16x8*)(qp + qd * 8);
    qf[mt][1] = *(const f16x8*)(qp + 32 + qd * 8);
  }
  float tv[4];
  for (int t = 0; t < 4; t++) tv[t] = Vtail[bh * HD_ + t * 16 + l15];

  f32x4 o[2][4] = {};
  float den[2][4] = {{0.f,0.f,0.f,0.f},{0.f,0.f,0.f,0.f}};

  // per-lane staging base pointers (tile offset added per iteration)
  const _Float16* kp       = Kn + (bh * S_ + skey) * HD_ + schunk;
  const unsigned short* vp = Vt + (bh * HD_ + skey) * S_ + schunk;

  // ---- prologue: stage tile 0 into buffer 0 ----
  GLD16(kp,      &Ks[0][0][0]  + tid * 8);
  GLD16(kp + 32, &Ks[0][1][0]  + tid * 8);
  GLD16(vp,      &Vts[0][0][0] + tid * 8);
  GLD16(vp + 32, &Vts[0][1][0] + tid * 8);
  __syncthreads();

  for (int kt = 0; kt < ntile; kt++) {
    int cur = kt & 1, nxt = cur ^ 1;

    // ---- issue next tile's stage FIRST (overlaps with all compute below).
    // Block-uniform branch; buffer `nxt` was last read in iteration kt-1,
    // whose end-of-tile barrier guarantees all waves are done with it.
    if (kt + 1 < ntile) {
      long koff = (long)(kt + 1) * 64 * HD_;   // K rows advance along S
      long voff = (long)(kt + 1) * 64;         // V^T cols advance along S
      GLD16(kp + koff,      &Ks[nxt][0][0]  + tid * 8);
      GLD16(kp + koff + 32, &Ks[nxt][1][0]  + tid * 8);
      GLD16(vp + voff,      &Vts[nxt][0][0] + tid * 8);
      GLD16(vp + voff + 32, &Vts[nxt][1][0] + tid * 8);
    }

    // ---- QK^T from buffer `cur` ----
    f32x4 sacc[2][4] = {};
    for (int tn = 0; tn < 4; tn++) {
      f16x8 kf0 = *(const f16x8*)(&Ks[cur][0][0] + (tn * 16 + l15) * 32 + qd * 8);
      f16x8 kf1 = *(const f16x8*)(&Ks[cur][1][0] + (tn * 16 + l15) * 32 + qd * 8);
      for (int mt = 0; mt < 2; mt++) {
        sacc[mt][tn] = __builtin_amdgcn_mfma_f32_16x16x32_f16(qf[mt][0], kf0, sacc[mt][tn], 0, 0, 0);
        sacc[mt][tn] = __builtin_amdgcn_mfma_f32_16x16x32_f16(qf[mt][1], kf1, sacc[mt][tn], 0, 0, 0);
      }
    }

    // ---- exp -> bf16 P (per-wave LDS buffer; no barrier needed) ----
    if (kt * 64 + 64 <= len) {
      // full tile: every key valid, no mask compare
      for (int mt = 0; mt < 2; mt++)
        for (int tn = 0; tn < 4; tn++)
          for (int r = 0; r < 4; r++) {
            float p = __expf(sacc[mt][tn][r]);
            unsigned short pb = f2bf(p);
            den[mt][r] += bf2f(pb);
            Ps[wave][(mt * 16 + qd * 4 + r) * 72 + tn * 16 + l15] = pb;
          }
    } else {
      for (int mt = 0; mt < 2; mt++)
        for (int tn = 0; tn < 4; tn++) {
          int kg = kt * 64 + tn * 16 + l15;
          bool valid = kg < len;
          for (int r = 0; r < 4; r++) {
            float p = valid ? __expf(sacc[mt][tn][r]) : 0.f;
            unsigned short pb = f2bf(p);
            den[mt][r] += bf2f(pb);
            Ps[wave][(mt * 16 + qd * 4 + r) * 72 + tn * 16 + l15] = pb;
          }
        }
    }

    // ---- P @ V^T from buffer `cur` ----
    bf16x8 pf[2][2];
    for (int mt = 0; mt < 2; mt++) {
      pf[mt][0] = *(const bf16x8*)(&Ps[wave][(mt * 16 + l15) * 72 + qd * 8]);
      pf[mt][1] = *(const bf16x8*)(&Ps[wave][(mt * 16 + l15) * 72 + 32 + qd * 8]);
    }
    for (int t = 0; t < 4; t++) {
      bf16x8 vf0 = *(const bf16x8*)(&Vts[cur][0][0] + (t * 16 + l15) * 32 + qd * 8);
      bf16x8 vf1 = *(const bf16x8*)(&Vts[cur][1][0] + (t * 16 + l15) * 32 + qd * 8);
      for (int mt = 0; mt < 2; mt++) {
        o[mt][t] = __builtin_amdgcn_mfma_f32_16x16x32_bf16(pf[mt][0], vf0, o[mt][t], 0, 0, 0);
        o[mt][t] = __builtin_amdgcn_mfma_f32_16x16x32_bf16(pf[mt][1], vf1, o[mt][t], 0, 0, 0);
      }
    }

    // single per-tile barrier: drains the prefetch (which has been in flight
    // under the whole tile's compute) and fences LDS buffer reuse.
    __syncthreads();
  }

  for (int mt = 0; mt < 2; mt++)
    for (int t = 0; t < 4; t++)
      for (int r = 0; r < 4; r++) o[mt][t][r] += tv[t];

  float tden = (float)(S_ - len);
  for (int mt = 0; mt < 2; mt++)
    for (int r = 0; r < 4; r++) {
      for (int off = 1; off < 16; off <<= 1)
        den[mt][r] += __shfl_xor(den[mt][r], off, 64);
      den[mt][r] += tden;
    }

  for (int mt = 0; mt < 2; mt++)
    for (int t = 0; t < 4; t++)
      for (int r = 0; r < 4; r++) {
        long s = q0 + wave * 32 + mt * 16 + qd * 4 + r;
        long dcol = (long)h * HD_ + t * 16 + l15;
        out[((long)b * S_ + s) * D_ + dcol] = o[mt][t][r] / den[mt][r];
      }
}

// ----------------------------------------------------------------- launch ---
extern "C" void kernel_launch(void* const* d_in, const int* in_sizes, int n_in,
                              void* d_out, int out_size, void* d_ws, size_t ws_size,
                              hipStream_t stream) {
  const float* x     = (const float*)d_in[0];
  const int*  seq    = (const int*)d_in[1];
  const float* Wq    = (const float*)d_in[2];
  const float* bq    = (const float*)d_in[3];
  const float* Wk    = (const float*)d_in[4];
  const float* bk    = (const float*)d_in[5];
  const float* Wv    = (const float*)d_in[6];
  const float* bv    = (const float*)d_in[7];
  const float* ln_g  = (const float*)d_in[8];
  const float* ln_b  = (const float*)d_in[9];
  float* out = (float*)d_out;

  char* ws = (char*)d_ws;
  _Float16* xh  = (_Float16*)(ws);                          // 8 MB
  _Float16* wqh = (_Float16*)(ws + (8l  << 20));            // 2 MB
  _Float16* wkh = (_Float16*)(ws + (10l << 20));            // 2 MB
  _Float16* wvh = (_Float16*)(ws + (12l << 20));            // 2 MB
  float*    Vtail = (float*)(ws + (14l << 20));             // 16 KB
  _Float16* qh  = (_Float16*)(ws + (16l << 20));            // 8 MB
  _Float16* kh  = (_Float16*)(ws + (24l << 20));            // 8 MB
  _Float16* vh  = (_Float16*)(ws + (32l << 20));            // 8 MB
  _Float16* Qn  = (_Float16*)(ws + (40l << 20));            // 8 MB
  _Float16* Kn  = (_Float16*)(ws + (48l << 20));            // 8 MB
  unsigned short* Vt = (unsigned short*)(ws + (56l << 20)); // 8 MB

  cvt_all<<<7172, 256, 0, stream>>>(x, xh, Wq, wqh, Wk, wkh, Wv, wvh, Vtail);

  dim3 g1(D_ / 64, (B_ * S_) / 128, 1);
  gemm_bt_bias<<<g1, 256, 0, stream>>>(xh, wqh, bq, qh, wqh, bq, qh,
                                       B_ * S_, D_, D_);
  dim3 g2(D_ / 128, (B_ * S_) / 128, 2);
  gemm_bt_bias128<<<g2, 256, 0, stream>>>(qh, wkh, bk, kh, wvh, bv, vh,
                                          B_ * S_, D_, D_);

  dim3 g3(S_ / 256, H_, B_);
  ln_qkv<<<g3, 256, 0, stream>>>(qh, kh, vh, ln_g, ln_b, seq, Qn, Kn, Vt, Vtail);

  dim3 g4(B_, H_, S_ / 128);
  attn<<<g4, 256, 0, stream>>>(Qn, Kn, Vt, Vtail, seq, out);
}